// Round 14
// baseline (228.801 us; speedup 1.0000x reference)
//
#include <hip/hip_runtime.h>
#include <hip/hip_bf16.h>

#define NN 10000
#define PP 32
#define QQ 64
#define EE 160000
#define FF 1024           // features per node = B*P, f = b*32 + p
#define NQ 640000         // N*Q
#define SLOTS 64          // edge slots per row (max degree; Poisson(16) tail ~1e-18)

typedef __attribute__((ext_vector_type(8))) short sh8;
typedef __attribute__((ext_vector_type(8))) __bf16 bf8v;
typedef __attribute__((ext_vector_type(4))) float f32x4;
typedef __attribute__((ext_vector_type(2))) float f32x2;
typedef __attribute__((ext_vector_type(4))) unsigned u32x4;

__device__ __forceinline__ short f2bf(float f) {
    return __builtin_bit_cast(short, __float2bfloat16(f));
}

// bf16 pair (one dword) -> two f32: lo = d<<16, hi = d & 0xffff0000
__device__ __forceinline__ f32x2 cvt2(unsigned d) {
    f32x2 r;
    r.x = __uint_as_float(d << 16);
    r.y = __uint_as_float(d & 0xffff0000u);
    return r;
}

// ---------------- init: zero cnt + prefill both edge-slot arrays ----------------
// ed1/ed2 contiguous: NN*SLOTS*2 u32 = 320000 uint4; cnt = 2*NN ints = 5000 uint4.
__global__ __launch_bounds__(256)
void init_kernel(unsigned* __restrict__ ed1, int* __restrict__ cnt) {
    int tid = blockIdx.x * 256 + threadIdx.x;
    if (tid < 320000) {
        *(u32x4*)(ed1 + (size_t)tid * 4) = (u32x4){0, 0, 0, 0};
    } else if (tid < 325000) {
        int i = tid - 320000;
        *(u32x4*)((unsigned*)cnt + (size_t)i * 4) = (u32x4){0, 0, 0, 0};
    }
}

// ---------------- fused prologue: WT prep + transpose + scatter (overlapped) -------------
// block 0: W[p*5+m][q] f32 -> wt[q][m*32+p] bf16.
// blocks 1..NN: transpose node n (inputs [B,N*P] -> x0[n][b*32+p] bf16).
// blocks NN+1..NN+625: scatter both graphs into 4B-packed {bf16 val | u16 col} slots.
__global__ __launch_bounds__(256)
void pre_kernel(const float* __restrict__ in, short* __restrict__ x0,
                const float* __restrict__ W, short* __restrict__ wt,
                const int* __restrict__ t1i, const float* __restrict__ t1v,
                const int* __restrict__ t2i, const float* __restrict__ t2v,
                int* __restrict__ cnt, unsigned* __restrict__ ed1, unsigned* __restrict__ ed2) {
    int t = threadIdx.x;
    int bx = blockIdx.x;
    if (bx == 0) {
#pragma unroll
        for (int j = 0; j < 40; ++j) {
            int idx = t + j * 256;          // 0..10239 = k*64 + q
            int k = idx >> 6, q = idx & 63;
            int p = k / 5;
            int m = k - p * 5;
            wt[q * 160 + m * 32 + p] = f2bf(W[idx]);
        }
        return;
    }
    if (bx <= NN) {
        int n = bx - 1;
        int b = t >> 3;
        int p0 = (t & 7) * 4;
        float4 v = *(const float4*)(in + (size_t)b * (NN * PP) + (size_t)n * PP + p0);
        short4 s = make_short4(f2bf(v.x), f2bf(v.y), f2bf(v.z), f2bf(v.w));
        *(short4*)(x0 + (size_t)n * FF + b * 32 + p0) = s;
        return;
    }
    // scatter: 625 blocks x 256 threads x 2 edges = 2*EE
    int tid = (bx - NN - 1) * 256 + t;
    const int* idx; const float* val; int* cn; unsigned* ed; int e0;
    if (tid < EE / 2) { idx = t1i; val = t1v; cn = cnt;      ed = ed1; e0 = tid * 2; }
    else              { idx = t2i; val = t2v; cn = cnt + NN; ed = ed2; e0 = (tid - EE / 2) * 2; }
    int2 rr = *(const int2*)(idx + e0);
    int2 cc = *(const int2*)(idx + EE + e0);
    float2 vv = *(const float2*)(val + e0);
    int pos0 = atomicAdd(&cn[rr.x], 1);
    if (pos0 < SLOTS)
        ed[rr.x * SLOTS + pos0] = ((unsigned)(unsigned short)f2bf(vv.x) << 16) | (unsigned)cc.x;
    int pos1 = atomicAdd(&cn[rr.y], 1);
    if (pos1 < SLOTS)
        ed[rr.y * SLOTS + pos1] = ((unsigned)(unsigned short)f2bf(vv.y) << 16) | (unsigned)cc.y;
}

// ---------------- degree-bucket sort: perm[g] = row ids in DESCENDING degree buckets ----
__global__ __launch_bounds__(1024)
void sort_kernel(const int* __restrict__ cnt, int* __restrict__ perm) {
    __shared__ int bins[65];
    __shared__ int base[65];
    int g = blockIdx.x;
    const int* cn = cnt + g * NN;
    int* pm = perm + g * NN;
    int t = threadIdx.x;
    if (t < 65) bins[t] = 0;
    __syncthreads();
    for (int i = t; i < NN; i += 1024) atomicAdd(&bins[min(cn[i], SLOTS)], 1);
    __syncthreads();
    if (t == 0) {
        int run = 0;
        for (int d = 64; d >= 0; --d) { base[d] = run; run += bins[d]; }
    }
    __syncthreads();
    if (t < 65) bins[t] = base[t];
    __syncthreads();
    for (int i = t; i < NN; i += 1024) {
        int d = min(cn[i], SLOTS);
        int pos = atomicAdd(&bins[d], 1);
        pm[pos] = i;
    }
}

// ---------------- SpMM: 4B edges, prefetch, degree-sorted, pk-FMA, XCD-affine, NT streams -
// Wave = 4 x 16-lane groups; group owns one row; 16 lanes x 8 bf16 = 128-elem chunk (256 B).
// Grid: bid = ((g * 625) + rb) * 8 + c -> 10000 blocks; XCD = bid%8 = c.
// ALL single-use streams (edge reads, sub reads, output stores) are nontemporal so the
// per-XCD L2 holds only the 16x-reused 2.56 MB x-slice; x gathers stay cached.
// Edge uint4 (4 edges) prefetched one iteration ahead. Slots pre-zeroed -> padding adds 0.
// out = bf16(alpha*(A@x) - (sub?sub:0)), accumulation f32.
__global__ __launch_bounds__(256)
void spmm_kernel(const int* __restrict__ cnt, const int* __restrict__ perm,
                 const unsigned* __restrict__ ed1, const unsigned* __restrict__ ed2,
                 const short* __restrict__ x1s, const short* __restrict__ x2s,
                 short* __restrict__ out1, short* __restrict__ out2,
                 const short* __restrict__ sub, float alpha) {
    int bid = blockIdx.x;
    int c = bid & 7;
    int rest = bid >> 3;
    int rb = rest % 625;
    int g = rest / 625;             // graph
    int fbase = c * 128;
    int wid  = threadIdx.x >> 6;
    int lane = threadIdx.x & 63;
    int grp  = lane >> 4;
    unsigned l16 = (unsigned)(lane & 15) * 16;   // byte offset within 256 B chunk
    int slot = rb * 16 + wid * 4 + grp;
    int n = perm[g * NN + slot];

    const u32x4* ep; const char* xb; short* out; int cn;
    if (g == 0) { ep = (const u32x4*)(ed1 + (size_t)n * SLOTS); xb = (const char*)x1s; out = out1; cn = cnt[n]; }
    else        { ep = (const u32x4*)(ed2 + (size_t)n * SLOTS); xb = (const char*)x2s; out = out2; cn = cnt[NN + n]; }
    xb += (unsigned)fbase * 2;      // wave-uniform chunk base
    cn = min(cn, SLOTS);
    int iters = (cn + 3) >> 2;

    f32x2 acc0 = {0.f, 0.f}, acc1 = {0.f, 0.f}, acc2 = {0.f, 0.f}, acc3 = {0.f, 0.f};

    u32x4 cur = __builtin_nontemporal_load(ep);
    for (int it = 0; it < iters; ++it) {
        u32x4 nxt = __builtin_nontemporal_load(ep + it + 1);  // prefetch next 4 edges
        unsigned o0 = ((cur.x & 0xffffu) << 11) | l16;
        unsigned o1 = ((cur.y & 0xffffu) << 11) | l16;
        unsigned o2 = ((cur.z & 0xffffu) << 11) | l16;
        unsigned o3 = ((cur.w & 0xffffu) << 11) | l16;
        u32x4 xa = *(const u32x4*)(xb + o0);
        u32x4 xb4 = *(const u32x4*)(xb + o1);
        u32x4 xc = *(const u32x4*)(xb + o2);
        u32x4 xd = *(const u32x4*)(xb + o3);
        float s0 = __uint_as_float(cur.x & 0xffff0000u);
        float s1 = __uint_as_float(cur.y & 0xffff0000u);
        float s2 = __uint_as_float(cur.z & 0xffff0000u);
        float s3 = __uint_as_float(cur.w & 0xffff0000u);
        f32x2 v0 = {s0, s0}, v1 = {s1, s1}, v2 = {s2, s2}, v3 = {s3, s3};
        acc0 += cvt2(xa.x) * v0; acc1 += cvt2(xa.y) * v0;
        acc2 += cvt2(xa.z) * v0; acc3 += cvt2(xa.w) * v0;
        acc0 += cvt2(xb4.x) * v1; acc1 += cvt2(xb4.y) * v1;
        acc2 += cvt2(xb4.z) * v1; acc3 += cvt2(xb4.w) * v1;
        acc0 += cvt2(xc.x) * v2; acc1 += cvt2(xc.y) * v2;
        acc2 += cvt2(xc.z) * v2; acc3 += cvt2(xc.w) * v2;
        acc0 += cvt2(xd.x) * v3; acc1 += cvt2(xd.y) * v3;
        acc2 += cvt2(xd.z) * v3; acc3 += cvt2(xd.w) * v3;
        cur = nxt;
    }

    float av[8];
    av[0] = acc0.x; av[1] = acc0.y; av[2] = acc1.x; av[3] = acc1.y;
    av[4] = acc2.x; av[5] = acc2.y; av[6] = acc3.x; av[7] = acc3.y;

    size_t obase = (size_t)n * FF + fbase + (l16 >> 1);
    sh8 o;
    if (sub) {
        u32x4 sv = __builtin_nontemporal_load((const u32x4*)((const char*)sub + obase * 2));
        bf8v s = __builtin_bit_cast(bf8v, sv);
#pragma unroll
        for (int j = 0; j < 8; ++j) o[j] = f2bf(alpha * av[j] - (float)s[j]);
    } else {
#pragma unroll
        for (int j = 0; j < 8; ++j) o[j] = f2bf(av[j]);
    }
    __builtin_nontemporal_store(o, (sh8*)(out + obase));
}

// ---------------- final GEMM via bf16 MFMA, no LDS, nontemporal stores ----------------
// item = (n-tile of 16, b). Wave computes D[64 q][16 n] for one b; exactly 4 items/wave.
// xs rows are reused x4 per XCD (32 b-items per nt) -> cached loads; out write-once -> NT.
__global__ __launch_bounds__(256)
void gemm_mfma_kernel(const short* __restrict__ xs, const short* __restrict__ wt,
                      const float* __restrict__ bias, float* __restrict__ out) {
    int t = threadIdx.x;
    int lane = t & 63;
    int gw = blockIdx.x * 4 + (t >> 6);     // global wave id, 0..4999
    int c = lane & 15, hi = lane >> 4;

    sh8 a0[5], a1[5], a2[5], a3[5];         // A-frags: 4 q-tiles x 5 ks
#pragma unroll
    for (int ks = 0; ks < 5; ++ks) {
        a0[ks] = *(const sh8*)(wt + (0 * 16 + c) * 160 + ks * 32 + hi * 8);
        a1[ks] = *(const sh8*)(wt + (1 * 16 + c) * 160 + ks * 32 + hi * 8);
        a2[ks] = *(const sh8*)(wt + (2 * 16 + c) * 160 + ks * 32 + hi * 8);
        a3[ks] = *(const sh8*)(wt + (3 * 16 + c) * 160 + ks * 32 + hi * 8);
    }
    float4 bv0 = *(const float4*)(bias + 0 * 16 + hi * 4);
    float4 bv1 = *(const float4*)(bias + 1 * 16 + hi * 4);
    float4 bv2 = *(const float4*)(bias + 2 * 16 + hi * 4);
    float4 bv3 = *(const float4*)(bias + 3 * 16 + hi * 4);

    for (int item = gw; item < 20000; item += 5000) {
        int b = item & 31, nt = item >> 5;
        const short* base = xs + (size_t)(nt * 16 + c) * FF + b * 32 + hi * 8;
        f32x4 acc0 = {0.f, 0.f, 0.f, 0.f};
        f32x4 acc1 = {0.f, 0.f, 0.f, 0.f};
        f32x4 acc2 = {0.f, 0.f, 0.f, 0.f};
        f32x4 acc3 = {0.f, 0.f, 0.f, 0.f};
#pragma unroll
        for (int ks = 0; ks < 5; ++ks) {
            sh8 bf = *(const sh8*)(base + (size_t)ks * ((size_t)NN * FF));
            acc0 = __builtin_amdgcn_mfma_f32_16x16x32_bf16(a0[ks], bf, acc0, 0, 0, 0);
            acc1 = __builtin_amdgcn_mfma_f32_16x16x32_bf16(a1[ks], bf, acc1, 0, 0, 0);
            acc2 = __builtin_amdgcn_mfma_f32_16x16x32_bf16(a2[ks], bf, acc2, 0, 0, 0);
            acc3 = __builtin_amdgcn_mfma_f32_16x16x32_bf16(a3[ks], bf, acc3, 0, 0, 0);
        }
        float* po = out + (size_t)b * NQ + (size_t)(nt * 16 + c) * 64 + hi * 4;
        f32x4 r0 = {acc0[0] + bv0.x, acc0[1] + bv0.y, acc0[2] + bv0.z, acc0[3] + bv0.w};
        f32x4 r1 = {acc1[0] + bv1.x, acc1[1] + bv1.y, acc1[2] + bv1.z, acc1[3] + bv1.w};
        f32x4 r2 = {acc2[0] + bv2.x, acc2[1] + bv2.y, acc2[2] + bv2.z, acc2[3] + bv2.w};
        f32x4 r3 = {acc3[0] + bv3.x, acc3[1] + bv3.y, acc3[2] + bv3.z, acc3[3] + bv3.w};
        __builtin_nontemporal_store(r0, (f32x4*)(po +  0));
        __builtin_nontemporal_store(r1, (f32x4*)(po + 16));
        __builtin_nontemporal_store(r2, (f32x4*)(po + 32));
        __builtin_nontemporal_store(r3, (f32x4*)(po + 48));
    }
}

extern "C" void kernel_launch(void* const* d_in, const int* in_sizes, int n_in,
                              void* d_out, int out_size, void* d_ws, size_t ws_size,
                              hipStream_t stream) {
    const float* inputs = (const float*)d_in[0];
    const int*   t1i    = (const int*)d_in[1];
    const float* t1v    = (const float*)d_in[2];
    const int*   t2i    = (const int*)d_in[3];
    const float* t2v    = (const float*)d_in[4];
    const float* W      = (const float*)d_in[5];
    const float* bias   = (const float*)d_in[6];
    float* out = (float*)d_out;

    short* ws = (short*)d_ws;
    const size_t NF = (size_t)NN * FF;          // elements per slab
    short* x0  = ws;                 // m = 0
    short* xs1 = ws + 1 * NF;        // m = 1 (t1, x1)
    short* xs2 = ws + 2 * NF;        // m = 2 (t1, x2)
    short* xs3 = ws + 3 * NF;        // m = 3 (t2, x1)
    short* xs4 = ws + 4 * NF;        // m = 4 (t2, x2)
    short* wt  = ws + 5 * NF;        // [64][160] bf16
    int* cnt  = (int*)(wt + 64 * 160);              // 2*NN counters
    unsigned* ed1 = (unsigned*)(cnt + 2 * NN);      // NN*SLOTS packed 4B edges, graph 1
    unsigned* ed2 = ed1 + (size_t)NN * SLOTS;       // graph 2
    int* perm = (int*)(ed2 + (size_t)NN * SLOTS);   // 2*NN degree-sorted row ids (also prefetch slack)

    init_kernel<<<1280, 256, 0, stream>>>(ed1, cnt);
    pre_kernel<<<NN + 1 + 625, 256, 0, stream>>>(inputs, x0, W, wt,
                                                 t1i, t1v, t2i, t2v, cnt, ed1, ed2);
    sort_kernel<<<2, 1024, 0, stream>>>(cnt, perm);

    const int spmm_grid = 2 * 625 * 8;   // 2 graphs x 625 row-blocks x 8 XCD chunks

    // step 1: x1 = A @ x0 (both transitions in one launch, XCD-affine chunks)
    spmm_kernel<<<spmm_grid, 256, 0, stream>>>(cnt, perm, ed1, ed2,
                                               x0, x0, xs1, xs3,
                                               nullptr, 1.0f);
    // step 2: x2 = 2 * (A @ x1) - x0 (fused Chebyshev epilogue)
    spmm_kernel<<<spmm_grid, 256, 0, stream>>>(cnt, perm, ed1, ed2,
                                               xs1, xs3, xs2, xs4,
                                               x0, 2.0f);

    gemm_mfma_kernel<<<1250, 256, 0, stream>>>(ws, wt, bias, out);
}

// Round 15
// 163.018 us; speedup vs baseline: 1.4035x; 1.4035x over previous
//
#include <hip/hip_runtime.h>
#include <hip/hip_bf16.h>

#define NN 10000
#define PP 32
#define QQ 64
#define EE 160000
#define FF 1024           // features per node = B*P, f = b*32 + p
#define NQ 640000         // N*Q
#define SLOTS 64          // edge slots per row (max degree; Poisson(16) tail ~1e-18)

typedef __attribute__((ext_vector_type(8))) short sh8;
typedef __attribute__((ext_vector_type(8))) __bf16 bf8v;
typedef __attribute__((ext_vector_type(4))) float f32x4;
typedef __attribute__((ext_vector_type(2))) float f32x2;
typedef __attribute__((ext_vector_type(4))) unsigned u32x4;

__device__ __forceinline__ short f2bf(float f) {
    return __builtin_bit_cast(short, __float2bfloat16(f));
}

// bf16 pair (one dword) -> two f32: lo = d<<16, hi = d & 0xffff0000
__device__ __forceinline__ f32x2 cvt2(unsigned d) {
    f32x2 r;
    r.x = __uint_as_float(d << 16);
    r.y = __uint_as_float(d & 0xffff0000u);
    return r;
}

// ---------------- init: zero cnt + prefill both edge-slot arrays ----------------
// ed1/ed2 contiguous: NN*SLOTS*2 u32 = 320000 uint4; cnt = 2*NN ints = 5000 uint4.
__global__ __launch_bounds__(256)
void init_kernel(unsigned* __restrict__ ed1, int* __restrict__ cnt) {
    int tid = blockIdx.x * 256 + threadIdx.x;
    if (tid < 320000) {
        *(u32x4*)(ed1 + (size_t)tid * 4) = (u32x4){0, 0, 0, 0};
    } else if (tid < 325000) {
        int i = tid - 320000;
        *(u32x4*)((unsigned*)cnt + (size_t)i * 4) = (u32x4){0, 0, 0, 0};
    }
}

// ---------------- fused prologue: WT prep + transpose + scatter (overlapped) -------------
// block 0: W[p*5+m][q] f32 -> wt[q][m*32+p] bf16.
// blocks 1..2500: transpose, contiguous-read grid-stride: in [B,N*P] -> x0[n][b*32+p] bf16
//                 (reads fully streaming; writes aligned 64B segments).
// blocks 2501..3125: scatter both graphs into 4B-packed {bf16 val | u16 col} slots.
__global__ __launch_bounds__(256)
void pre_kernel(const float* __restrict__ in, short* __restrict__ x0,
                const float* __restrict__ W, short* __restrict__ wt,
                const int* __restrict__ t1i, const float* __restrict__ t1v,
                const int* __restrict__ t2i, const float* __restrict__ t2v,
                int* __restrict__ cnt, unsigned* __restrict__ ed1, unsigned* __restrict__ ed2) {
    int t = threadIdx.x;
    int bx = blockIdx.x;
    if (bx == 0) {
#pragma unroll
        for (int j = 0; j < 40; ++j) {
            int idx = t + j * 256;          // 0..10239 = k*64 + q
            int k = idx >> 6, q = idx & 63;
            int p = k / 5;
            int m = k - p * 5;
            wt[q * 160 + m * 32 + p] = f2bf(W[idx]);
        }
        return;
    }
    if (bx <= 2500) {
        // 2500 blocks x 4 iters x 256 threads = 2.56M float4 = all of in
        const float4* in4 = (const float4*)in;
#pragma unroll
        for (int j = 0; j < 4; ++j) {
            int idx = (bx - 1) * 1024 + j * 256 + t;    // global float4 index
            int b = idx / 80000;                         // NN*PP/4 = 80000 per batch row
            int rem = idx - b * 80000;
            int n = rem >> 3;
            int p04 = rem & 7;
            float4 v = in4[idx];
            short4 s = make_short4(f2bf(v.x), f2bf(v.y), f2bf(v.z), f2bf(v.w));
            *(short4*)(x0 + (size_t)n * FF + b * 32 + p04 * 4) = s;
        }
        return;
    }
    // scatter: 625 blocks x 256 threads x 2 edges = 2*EE
    int tid = (bx - 2501) * 256 + t;
    const int* idx; const float* val; int* cn; unsigned* ed; int e0;
    if (tid < EE / 2) { idx = t1i; val = t1v; cn = cnt;      ed = ed1; e0 = tid * 2; }
    else              { idx = t2i; val = t2v; cn = cnt + NN; ed = ed2; e0 = (tid - EE / 2) * 2; }
    int2 rr = *(const int2*)(idx + e0);
    int2 cc = *(const int2*)(idx + EE + e0);
    float2 vv = *(const float2*)(val + e0);
    int pos0 = atomicAdd(&cn[rr.x], 1);
    if (pos0 < SLOTS)
        ed[rr.x * SLOTS + pos0] = ((unsigned)(unsigned short)f2bf(vv.x) << 16) | (unsigned)cc.x;
    int pos1 = atomicAdd(&cn[rr.y], 1);
    if (pos1 < SLOTS)
        ed[rr.y * SLOTS + pos1] = ((unsigned)(unsigned short)f2bf(vv.y) << 16) | (unsigned)cc.y;
}

// ---------------- degree-bucket sort: perm[g] = row ids in DESCENDING degree buckets ----
__global__ __launch_bounds__(1024)
void sort_kernel(const int* __restrict__ cnt, int* __restrict__ perm) {
    __shared__ int bins[65];
    __shared__ int base[65];
    int g = blockIdx.x;
    const int* cn = cnt + g * NN;
    int* pm = perm + g * NN;
    int t = threadIdx.x;
    if (t < 65) bins[t] = 0;
    __syncthreads();
    for (int i = t; i < NN; i += 1024) atomicAdd(&bins[min(cn[i], SLOTS)], 1);
    __syncthreads();
    if (t == 0) {
        int run = 0;
        for (int d = 64; d >= 0; --d) { base[d] = run; run += bins[d]; }
    }
    __syncthreads();
    if (t < 65) bins[t] = base[t];
    __syncthreads();
    for (int i = t; i < NN; i += 1024) {
        int d = min(cn[i], SLOTS);
        int pos = atomicAdd(&bins[d], 1);
        pm[pos] = i;
    }
}

// ---------------- SpMM: 8 edges/iter, sorted rows, pk-FMA, XCD-affine --------------------
// Wave = 4 x 16-lane groups; group owns one row; 16 lanes x 8 bf16 = 128-elem chunk (256 B).
// Grid: bid = ((g * 625) + rb) * 8 + c -> 10000 blocks; XCD = bid%8 = c;
// per-XCD live x-slice = 2.56 MB < 4 MiB L2. Degree-sorted rows -> the 4 rows in a wave
// have near-equal degree -> iterations = ceil(d/8) with no divergence waste; 8 gathers
// in flight per iteration (2x the MLP of the 4-edge loop). Edge uint4 pair prefetched one
// iteration ahead. Slots pre-zeroed -> padded edges contribute 0; prefetch overrun <=32B
// lands in the next row's slots / perm area.
// out = bf16(alpha*(A@x) - (sub?sub:0)), accumulation f32.
__global__ __launch_bounds__(256)
void spmm_kernel(const int* __restrict__ cnt, const int* __restrict__ perm,
                 const unsigned* __restrict__ ed1, const unsigned* __restrict__ ed2,
                 const short* __restrict__ x1s, const short* __restrict__ x2s,
                 short* __restrict__ out1, short* __restrict__ out2,
                 const short* __restrict__ sub, float alpha) {
    int bid = blockIdx.x;
    int c = bid & 7;
    int rest = bid >> 3;
    int rb = rest % 625;
    int g = rest / 625;             // graph
    int fbase = c * 128;
    int wid  = threadIdx.x >> 6;
    int lane = threadIdx.x & 63;
    int grp  = lane >> 4;
    unsigned l16 = (unsigned)(lane & 15) * 16;   // byte offset within 256 B chunk
    int slot = rb * 16 + wid * 4 + grp;
    int n = perm[g * NN + slot];

    const u32x4* ep; const char* xb; short* out; int cn;
    if (g == 0) { ep = (const u32x4*)(ed1 + (size_t)n * SLOTS); xb = (const char*)x1s; out = out1; cn = cnt[n]; }
    else        { ep = (const u32x4*)(ed2 + (size_t)n * SLOTS); xb = (const char*)x2s; out = out2; cn = cnt[NN + n]; }
    xb += (unsigned)fbase * 2;      // wave-uniform chunk base
    cn = min(cn, SLOTS);
    int iters = (cn + 7) >> 3;

    f32x2 acc0 = {0.f, 0.f}, acc1 = {0.f, 0.f}, acc2 = {0.f, 0.f}, acc3 = {0.f, 0.f};

    u32x4 cA = ep[0];
    u32x4 cB = ep[1];
    for (int it = 0; it < iters; ++it) {
        u32x4 nA = ep[2 * it + 2];      // prefetch next 8 edges
        u32x4 nB = ep[2 * it + 3];
        unsigned o0 = ((cA.x & 0xffffu) << 11) | l16;
        unsigned o1 = ((cA.y & 0xffffu) << 11) | l16;
        unsigned o2 = ((cA.z & 0xffffu) << 11) | l16;
        unsigned o3 = ((cA.w & 0xffffu) << 11) | l16;
        unsigned o4 = ((cB.x & 0xffffu) << 11) | l16;
        unsigned o5 = ((cB.y & 0xffffu) << 11) | l16;
        unsigned o6 = ((cB.z & 0xffffu) << 11) | l16;
        unsigned o7 = ((cB.w & 0xffffu) << 11) | l16;
        u32x4 xv0 = *(const u32x4*)(xb + o0);
        u32x4 xv1 = *(const u32x4*)(xb + o1);
        u32x4 xv2 = *(const u32x4*)(xb + o2);
        u32x4 xv3 = *(const u32x4*)(xb + o3);
        u32x4 xv4 = *(const u32x4*)(xb + o4);
        u32x4 xv5 = *(const u32x4*)(xb + o5);
        u32x4 xv6 = *(const u32x4*)(xb + o6);
        u32x4 xv7 = *(const u32x4*)(xb + o7);
        float s0 = __uint_as_float(cA.x & 0xffff0000u);
        float s1 = __uint_as_float(cA.y & 0xffff0000u);
        float s2 = __uint_as_float(cA.z & 0xffff0000u);
        float s3 = __uint_as_float(cA.w & 0xffff0000u);
        float s4 = __uint_as_float(cB.x & 0xffff0000u);
        float s5 = __uint_as_float(cB.y & 0xffff0000u);
        float s6 = __uint_as_float(cB.z & 0xffff0000u);
        float s7 = __uint_as_float(cB.w & 0xffff0000u);
        f32x2 v0 = {s0, s0}, v1 = {s1, s1}, v2 = {s2, s2}, v3 = {s3, s3};
        f32x2 v4 = {s4, s4}, v5 = {s5, s5}, v6 = {s6, s6}, v7 = {s7, s7};
        acc0 += cvt2(xv0.x) * v0; acc1 += cvt2(xv0.y) * v0;
        acc2 += cvt2(xv0.z) * v0; acc3 += cvt2(xv0.w) * v0;
        acc0 += cvt2(xv1.x) * v1; acc1 += cvt2(xv1.y) * v1;
        acc2 += cvt2(xv1.z) * v1; acc3 += cvt2(xv1.w) * v1;
        acc0 += cvt2(xv2.x) * v2; acc1 += cvt2(xv2.y) * v2;
        acc2 += cvt2(xv2.z) * v2; acc3 += cvt2(xv2.w) * v2;
        acc0 += cvt2(xv3.x) * v3; acc1 += cvt2(xv3.y) * v3;
        acc2 += cvt2(xv3.z) * v3; acc3 += cvt2(xv3.w) * v3;
        acc0 += cvt2(xv4.x) * v4; acc1 += cvt2(xv4.y) * v4;
        acc2 += cvt2(xv4.z) * v4; acc3 += cvt2(xv4.w) * v4;
        acc0 += cvt2(xv5.x) * v5; acc1 += cvt2(xv5.y) * v5;
        acc2 += cvt2(xv5.z) * v5; acc3 += cvt2(xv5.w) * v5;
        acc0 += cvt2(xv6.x) * v6; acc1 += cvt2(xv6.y) * v6;
        acc2 += cvt2(xv6.z) * v6; acc3 += cvt2(xv6.w) * v6;
        acc0 += cvt2(xv7.x) * v7; acc1 += cvt2(xv7.y) * v7;
        acc2 += cvt2(xv7.z) * v7; acc3 += cvt2(xv7.w) * v7;
        cA = nA; cB = nB;
    }

    float av[8];
    av[0] = acc0.x; av[1] = acc0.y; av[2] = acc1.x; av[3] = acc1.y;
    av[4] = acc2.x; av[5] = acc2.y; av[6] = acc3.x; av[7] = acc3.y;

    size_t obase = (size_t)n * FF + fbase + (l16 >> 1);
    sh8 o;
    if (sub) {
        bf8v s = *(const bf8v*)((const __bf16*)sub + obase);
#pragma unroll
        for (int j = 0; j < 8; ++j) o[j] = f2bf(alpha * av[j] - (float)s[j]);
    } else {
#pragma unroll
        for (int j = 0; j < 8; ++j) o[j] = f2bf(av[j]);
    }
    *(sh8*)(out + obase) = o;
}

// ---------------- final GEMM via bf16 MFMA, no LDS, nontemporal stores ----------------
// item = (n-tile of 16, b). Wave computes D[64 q][16 n] for one b; exactly 4 items/wave.
__global__ __launch_bounds__(256)
void gemm_mfma_kernel(const short* __restrict__ xs, const short* __restrict__ wt,
                      const float* __restrict__ bias, float* __restrict__ out) {
    int t = threadIdx.x;
    int lane = t & 63;
    int gw = blockIdx.x * 4 + (t >> 6);     // global wave id, 0..4999
    int c = lane & 15, hi = lane >> 4;

    sh8 a0[5], a1[5], a2[5], a3[5];         // A-frags: 4 q-tiles x 5 ks
#pragma unroll
    for (int ks = 0; ks < 5; ++ks) {
        a0[ks] = *(const sh8*)(wt + (0 * 16 + c) * 160 + ks * 32 + hi * 8);
        a1[ks] = *(const sh8*)(wt + (1 * 16 + c) * 160 + ks * 32 + hi * 8);
        a2[ks] = *(const sh8*)(wt + (2 * 16 + c) * 160 + ks * 32 + hi * 8);
        a3[ks] = *(const sh8*)(wt + (3 * 16 + c) * 160 + ks * 32 + hi * 8);
    }
    float4 bv0 = *(const float4*)(bias + 0 * 16 + hi * 4);
    float4 bv1 = *(const float4*)(bias + 1 * 16 + hi * 4);
    float4 bv2 = *(const float4*)(bias + 2 * 16 + hi * 4);
    float4 bv3 = *(const float4*)(bias + 3 * 16 + hi * 4);

    for (int item = gw; item < 20000; item += 5000) {
        int b = item & 31, nt = item >> 5;
        const short* base = xs + (size_t)(nt * 16 + c) * FF + b * 32 + hi * 8;
        f32x4 acc0 = {0.f, 0.f, 0.f, 0.f};
        f32x4 acc1 = {0.f, 0.f, 0.f, 0.f};
        f32x4 acc2 = {0.f, 0.f, 0.f, 0.f};
        f32x4 acc3 = {0.f, 0.f, 0.f, 0.f};
#pragma unroll
        for (int ks = 0; ks < 5; ++ks) {
            sh8 bf = *(const sh8*)(base + (size_t)ks * ((size_t)NN * FF));
            acc0 = __builtin_amdgcn_mfma_f32_16x16x32_bf16(a0[ks], bf, acc0, 0, 0, 0);
            acc1 = __builtin_amdgcn_mfma_f32_16x16x32_bf16(a1[ks], bf, acc1, 0, 0, 0);
            acc2 = __builtin_amdgcn_mfma_f32_16x16x32_bf16(a2[ks], bf, acc2, 0, 0, 0);
            acc3 = __builtin_amdgcn_mfma_f32_16x16x32_bf16(a3[ks], bf, acc3, 0, 0, 0);
        }
        float* po = out + (size_t)b * NQ + (size_t)(nt * 16 + c) * 64 + hi * 4;
        f32x4 r0 = {acc0[0] + bv0.x, acc0[1] + bv0.y, acc0[2] + bv0.z, acc0[3] + bv0.w};
        f32x4 r1 = {acc1[0] + bv1.x, acc1[1] + bv1.y, acc1[2] + bv1.z, acc1[3] + bv1.w};
        f32x4 r2 = {acc2[0] + bv2.x, acc2[1] + bv2.y, acc2[2] + bv2.z, acc2[3] + bv2.w};
        f32x4 r3 = {acc3[0] + bv3.x, acc3[1] + bv3.y, acc3[2] + bv3.z, acc3[3] + bv3.w};
        __builtin_nontemporal_store(r0, (f32x4*)(po +  0));
        __builtin_nontemporal_store(r1, (f32x4*)(po + 16));
        __builtin_nontemporal_store(r2, (f32x4*)(po + 32));
        __builtin_nontemporal_store(r3, (f32x4*)(po + 48));
    }
}

extern "C" void kernel_launch(void* const* d_in, const int* in_sizes, int n_in,
                              void* d_out, int out_size, void* d_ws, size_t ws_size,
                              hipStream_t stream) {
    const float* inputs = (const float*)d_in[0];
    const int*   t1i    = (const int*)d_in[1];
    const float* t1v    = (const float*)d_in[2];
    const int*   t2i    = (const int*)d_in[3];
    const float* t2v    = (const float*)d_in[4];
    const float* W      = (const float*)d_in[5];
    const float* bias   = (const float*)d_in[6];
    float* out = (float*)d_out;

    short* ws = (short*)d_ws;
    const size_t NF = (size_t)NN * FF;          // elements per slab
    short* x0  = ws;                 // m = 0
    short* xs1 = ws + 1 * NF;        // m = 1 (t1, x1)
    short* xs2 = ws + 2 * NF;        // m = 2 (t1, x2)
    short* xs3 = ws + 3 * NF;        // m = 3 (t2, x1)
    short* xs4 = ws + 4 * NF;        // m = 4 (t2, x2)
    short* wt  = ws + 5 * NF;        // [64][160] bf16
    int* cnt  = (int*)(wt + 64 * 160);              // 2*NN counters
    unsigned* ed1 = (unsigned*)(cnt + 2 * NN);      // NN*SLOTS packed 4B edges, graph 1
    unsigned* ed2 = ed1 + (size_t)NN * SLOTS;       // graph 2
    int* perm = (int*)(ed2 + (size_t)NN * SLOTS);   // 2*NN degree-sorted row ids (also prefetch slack)

    init_kernel<<<1280, 256, 0, stream>>>(ed1, cnt);
    pre_kernel<<<1 + 2500 + 625, 256, 0, stream>>>(inputs, x0, W, wt,
                                                   t1i, t1v, t2i, t2v, cnt, ed1, ed2);
    sort_kernel<<<2, 1024, 0, stream>>>(cnt, perm);

    const int spmm_grid = 2 * 625 * 8;   // 2 graphs x 625 row-blocks x 8 XCD chunks

    // step 1: x1 = A @ x0 (both transitions in one launch, XCD-affine chunks)
    spmm_kernel<<<spmm_grid, 256, 0, stream>>>(cnt, perm, ed1, ed2,
                                               x0, x0, xs1, xs3,
                                               nullptr, 1.0f);
    // step 2: x2 = 2 * (A @ x1) - x0 (fused Chebyshev epilogue)
    spmm_kernel<<<spmm_grid, 256, 0, stream>>>(cnt, perm, ed1, ed2,
                                               xs1, xs3, xs2, xs4,
                                               x0, 2.0f);

    gemm_mfma_kernel<<<1250, 256, 0, stream>>>(ws, wt, bias, out);
}

// Round 16
// 158.781 us; speedup vs baseline: 1.4410x; 1.0267x over previous
//
#include <hip/hip_runtime.h>
#include <hip/hip_bf16.h>

#define NN 10000
#define PP 32
#define QQ 64
#define EE 160000
#define FF 1024           // features per node = B*P, f = b*32 + p
#define NQ 640000         // N*Q
#define SLOTS 64          // edge slots per row (max degree; Poisson(16) tail ~1e-18)

typedef __attribute__((ext_vector_type(8))) short sh8;
typedef __attribute__((ext_vector_type(8))) __bf16 bf8v;
typedef __attribute__((ext_vector_type(4))) float f32x4;
typedef __attribute__((ext_vector_type(2))) float f32x2;
typedef __attribute__((ext_vector_type(4))) unsigned u32x4;

__device__ __forceinline__ short f2bf(float f) {
    return __builtin_bit_cast(short, __float2bfloat16(f));
}

// bf16 pair (one dword) -> two f32: lo = d<<16, hi = d & 0xffff0000
__device__ __forceinline__ f32x2 cvt2(unsigned d) {
    f32x2 r;
    r.x = __uint_as_float(d << 16);
    r.y = __uint_as_float(d & 0xffff0000u);
    return r;
}

// ---------------- init: zero cnt + prefill both edge-slot arrays ----------------
// ed1/ed2 contiguous: NN*SLOTS*2 u32 = 320000 uint4; cnt = 2*NN ints = 5000 uint4.
__global__ __launch_bounds__(256)
void init_kernel(unsigned* __restrict__ ed1, int* __restrict__ cnt) {
    int tid = blockIdx.x * 256 + threadIdx.x;
    if (tid < 320000) {
        *(u32x4*)(ed1 + (size_t)tid * 4) = (u32x4){0, 0, 0, 0};
    } else if (tid < 325000) {
        int i = tid - 320000;
        *(u32x4*)((unsigned*)cnt + (size_t)i * 4) = (u32x4){0, 0, 0, 0};
    }
}

// ---------------- fused prologue: WT prep + transpose + scatter (overlapped) -------------
// block 0: W[p*5+m][q] f32 -> wt[q][m*32+p] bf16.
// blocks 1..2500: transpose, contiguous-read grid-stride: in [B,N*P] -> x0[n][b*32+p] bf16
//                 (reads fully streaming; writes aligned 64B segments).
// blocks 2501..3125: scatter both graphs into 4B-packed {bf16 val | u16 col} slots.
__global__ __launch_bounds__(256)
void pre_kernel(const float* __restrict__ in, short* __restrict__ x0,
                const float* __restrict__ W, short* __restrict__ wt,
                const int* __restrict__ t1i, const float* __restrict__ t1v,
                const int* __restrict__ t2i, const float* __restrict__ t2v,
                int* __restrict__ cnt, unsigned* __restrict__ ed1, unsigned* __restrict__ ed2) {
    int t = threadIdx.x;
    int bx = blockIdx.x;
    if (bx == 0) {
#pragma unroll
        for (int j = 0; j < 40; ++j) {
            int idx = t + j * 256;          // 0..10239 = k*64 + q
            int k = idx >> 6, q = idx & 63;
            int p = k / 5;
            int m = k - p * 5;
            wt[q * 160 + m * 32 + p] = f2bf(W[idx]);
        }
        return;
    }
    if (bx <= 2500) {
        // 2500 blocks x 4 iters x 256 threads = 2.56M float4 = all of in
        const float4* in4 = (const float4*)in;
#pragma unroll
        for (int j = 0; j < 4; ++j) {
            int idx = (bx - 1) * 1024 + j * 256 + t;    // global float4 index
            int b = idx / 80000;                         // NN*PP/4 = 80000 per batch row
            int rem = idx - b * 80000;
            int n = rem >> 3;
            int p04 = rem & 7;
            float4 v = in4[idx];
            short4 s = make_short4(f2bf(v.x), f2bf(v.y), f2bf(v.z), f2bf(v.w));
            *(short4*)(x0 + (size_t)n * FF + b * 32 + p04 * 4) = s;
        }
        return;
    }
    // scatter: 625 blocks x 256 threads x 2 edges = 2*EE
    int tid = (bx - 2501) * 256 + t;
    const int* idx; const float* val; int* cn; unsigned* ed; int e0;
    if (tid < EE / 2) { idx = t1i; val = t1v; cn = cnt;      ed = ed1; e0 = tid * 2; }
    else              { idx = t2i; val = t2v; cn = cnt + NN; ed = ed2; e0 = (tid - EE / 2) * 2; }
    int2 rr = *(const int2*)(idx + e0);
    int2 cc = *(const int2*)(idx + EE + e0);
    float2 vv = *(const float2*)(val + e0);
    int pos0 = atomicAdd(&cn[rr.x], 1);
    if (pos0 < SLOTS)
        ed[rr.x * SLOTS + pos0] = ((unsigned)(unsigned short)f2bf(vv.x) << 16) | (unsigned)cc.x;
    int pos1 = atomicAdd(&cn[rr.y], 1);
    if (pos1 < SLOTS)
        ed[rr.y * SLOTS + pos1] = ((unsigned)(unsigned short)f2bf(vv.y) << 16) | (unsigned)cc.y;
}

// ---------------- degree-bucket sort: perm[g] = row ids in DESCENDING degree buckets ----
__global__ __launch_bounds__(1024)
void sort_kernel(const int* __restrict__ cnt, int* __restrict__ perm) {
    __shared__ int bins[65];
    __shared__ int base[65];
    int g = blockIdx.x;
    const int* cn = cnt + g * NN;
    int* pm = perm + g * NN;
    int t = threadIdx.x;
    if (t < 65) bins[t] = 0;
    __syncthreads();
    for (int i = t; i < NN; i += 1024) atomicAdd(&bins[min(cn[i], SLOTS)], 1);
    __syncthreads();
    if (t == 0) {
        int run = 0;
        for (int d = 64; d >= 0; --d) { base[d] = run; run += bins[d]; }
    }
    __syncthreads();
    if (t < 65) bins[t] = base[t];
    __syncthreads();
    for (int i = t; i < NN; i += 1024) {
        int d = min(cn[i], SLOTS);
        int pos = atomicAdd(&bins[d], 1);
        pm[pos] = i;
    }
}

// ---------------- SpMM: 4B edges, edge-prefetch, degree-sorted, pk-FMA, XCD-affine -------
// (R10 kernel, verbatim — empirical optimum over 8 structural variants, ~44-46 us.)
// Wave = 4 x 16-lane groups; group owns one row; 16 lanes x 8 bf16 = 128-elem chunk (256 B).
// Grid: bid = ((g * 625) + rb) * 8 + c -> 10000 blocks; XCD = bid%8 = c;
// per-XCD live x-slice = 2.56 MB < 4 MiB L2. Degree-sorted rows -> near-uniform trip
// count per wave. Edge uint4 (4 edges) prefetched one iteration ahead. Slots pre-zeroed
// -> padding adds 0; prefetch overrun lands in next row / perm slack.
// out = bf16(alpha*(A@x) - (sub?sub:0)), accumulation f32.
__global__ __launch_bounds__(256)
void spmm_kernel(const int* __restrict__ cnt, const int* __restrict__ perm,
                 const unsigned* __restrict__ ed1, const unsigned* __restrict__ ed2,
                 const short* __restrict__ x1s, const short* __restrict__ x2s,
                 short* __restrict__ out1, short* __restrict__ out2,
                 const short* __restrict__ sub, float alpha) {
    int bid = blockIdx.x;
    int c = bid & 7;
    int rest = bid >> 3;
    int rb = rest % 625;
    int g = rest / 625;             // graph
    int fbase = c * 128;
    int wid  = threadIdx.x >> 6;
    int lane = threadIdx.x & 63;
    int grp  = lane >> 4;
    unsigned l16 = (unsigned)(lane & 15) * 16;   // byte offset within 256 B chunk
    int slot = rb * 16 + wid * 4 + grp;
    int n = perm[g * NN + slot];

    const u32x4* ep; const char* xb; short* out; int cn;
    if (g == 0) { ep = (const u32x4*)(ed1 + (size_t)n * SLOTS); xb = (const char*)x1s; out = out1; cn = cnt[n]; }
    else        { ep = (const u32x4*)(ed2 + (size_t)n * SLOTS); xb = (const char*)x2s; out = out2; cn = cnt[NN + n]; }
    xb += (unsigned)fbase * 2;      // wave-uniform chunk base
    cn = min(cn, SLOTS);
    int iters = (cn + 3) >> 2;

    f32x2 acc0 = {0.f, 0.f}, acc1 = {0.f, 0.f}, acc2 = {0.f, 0.f}, acc3 = {0.f, 0.f};

    u32x4 cur = ep[0];
    for (int it = 0; it < iters; ++it) {
        u32x4 nxt = ep[it + 1];     // prefetch next 4 edges (latency hidden under this iter)
        unsigned o0 = ((cur.x & 0xffffu) << 11) | l16;
        unsigned o1 = ((cur.y & 0xffffu) << 11) | l16;
        unsigned o2 = ((cur.z & 0xffffu) << 11) | l16;
        unsigned o3 = ((cur.w & 0xffffu) << 11) | l16;
        u32x4 xa = *(const u32x4*)(xb + o0);
        u32x4 xb4 = *(const u32x4*)(xb + o1);
        u32x4 xc = *(const u32x4*)(xb + o2);
        u32x4 xd = *(const u32x4*)(xb + o3);
        float s0 = __uint_as_float(cur.x & 0xffff0000u);
        float s1 = __uint_as_float(cur.y & 0xffff0000u);
        float s2 = __uint_as_float(cur.z & 0xffff0000u);
        float s3 = __uint_as_float(cur.w & 0xffff0000u);
        f32x2 v0 = {s0, s0}, v1 = {s1, s1}, v2 = {s2, s2}, v3 = {s3, s3};
        acc0 += cvt2(xa.x) * v0; acc1 += cvt2(xa.y) * v0;
        acc2 += cvt2(xa.z) * v0; acc3 += cvt2(xa.w) * v0;
        acc0 += cvt2(xb4.x) * v1; acc1 += cvt2(xb4.y) * v1;
        acc2 += cvt2(xb4.z) * v1; acc3 += cvt2(xb4.w) * v1;
        acc0 += cvt2(xc.x) * v2; acc1 += cvt2(xc.y) * v2;
        acc2 += cvt2(xc.z) * v2; acc3 += cvt2(xc.w) * v2;
        acc0 += cvt2(xd.x) * v3; acc1 += cvt2(xd.y) * v3;
        acc2 += cvt2(xd.z) * v3; acc3 += cvt2(xd.w) * v3;
        cur = nxt;
    }

    float av[8];
    av[0] = acc0.x; av[1] = acc0.y; av[2] = acc1.x; av[3] = acc1.y;
    av[4] = acc2.x; av[5] = acc2.y; av[6] = acc3.x; av[7] = acc3.y;

    size_t obase = (size_t)n * FF + fbase + (l16 >> 1);
    sh8 o;
    if (sub) {
        bf8v s = *(const bf8v*)((const __bf16*)sub + obase);
#pragma unroll
        for (int j = 0; j < 8; ++j) o[j] = f2bf(alpha * av[j] - (float)s[j]);
    } else {
#pragma unroll
        for (int j = 0; j < 8; ++j) o[j] = f2bf(av[j]);
    }
    *(sh8*)(out + obase) = o;
}

// ---------------- final GEMM via bf16 MFMA, no LDS, nontemporal stores ----------------
// item = (n-tile of 16, b). Wave computes D[64 q][16 n] for one b; exactly 4 items/wave.
// xs rows reused x4 per XCD -> cached loads; out write-once -> NT stores.
__global__ __launch_bounds__(256)
void gemm_mfma_kernel(const short* __restrict__ xs, const short* __restrict__ wt,
                      const float* __restrict__ bias, float* __restrict__ out) {
    int t = threadIdx.x;
    int lane = t & 63;
    int gw = blockIdx.x * 4 + (t >> 6);     // global wave id, 0..4999
    int c = lane & 15, hi = lane >> 4;

    sh8 a0[5], a1[5], a2[5], a3[5];         // A-frags: 4 q-tiles x 5 ks
#pragma unroll
    for (int ks = 0; ks < 5; ++ks) {
        a0[ks] = *(const sh8*)(wt + (0 * 16 + c) * 160 + ks * 32 + hi * 8);
        a1[ks] = *(const sh8*)(wt + (1 * 16 + c) * 160 + ks * 32 + hi * 8);
        a2[ks] = *(const sh8*)(wt + (2 * 16 + c) * 160 + ks * 32 + hi * 8);
        a3[ks] = *(const sh8*)(wt + (3 * 16 + c) * 160 + ks * 32 + hi * 8);
    }
    float4 bv0 = *(const float4*)(bias + 0 * 16 + hi * 4);
    float4 bv1 = *(const float4*)(bias + 1 * 16 + hi * 4);
    float4 bv2 = *(const float4*)(bias + 2 * 16 + hi * 4);
    float4 bv3 = *(const float4*)(bias + 3 * 16 + hi * 4);

    for (int item = gw; item < 20000; item += 5000) {
        int b = item & 31, nt = item >> 5;
        const short* base = xs + (size_t)(nt * 16 + c) * FF + b * 32 + hi * 8;
        f32x4 acc0 = {0.f, 0.f, 0.f, 0.f};
        f32x4 acc1 = {0.f, 0.f, 0.f, 0.f};
        f32x4 acc2 = {0.f, 0.f, 0.f, 0.f};
        f32x4 acc3 = {0.f, 0.f, 0.f, 0.f};
#pragma unroll
        for (int ks = 0; ks < 5; ++ks) {
            sh8 bf = *(const sh8*)(base + (size_t)ks * ((size_t)NN * FF));
            acc0 = __builtin_amdgcn_mfma_f32_16x16x32_bf16(a0[ks], bf, acc0, 0, 0, 0);
            acc1 = __builtin_amdgcn_mfma_f32_16x16x32_bf16(a1[ks], bf, acc1, 0, 0, 0);
            acc2 = __builtin_amdgcn_mfma_f32_16x16x32_bf16(a2[ks], bf, acc2, 0, 0, 0);
            acc3 = __builtin_amdgcn_mfma_f32_16x16x32_bf16(a3[ks], bf, acc3, 0, 0, 0);
        }
        float* po = out + (size_t)b * NQ + (size_t)(nt * 16 + c) * 64 + hi * 4;
        f32x4 r0 = {acc0[0] + bv0.x, acc0[1] + bv0.y, acc0[2] + bv0.z, acc0[3] + bv0.w};
        f32x4 r1 = {acc1[0] + bv1.x, acc1[1] + bv1.y, acc1[2] + bv1.z, acc1[3] + bv1.w};
        f32x4 r2 = {acc2[0] + bv2.x, acc2[1] + bv2.y, acc2[2] + bv2.z, acc2[3] + bv2.w};
        f32x4 r3 = {acc3[0] + bv3.x, acc3[1] + bv3.y, acc3[2] + bv3.z, acc3[3] + bv3.w};
        __builtin_nontemporal_store(r0, (f32x4*)(po +  0));
        __builtin_nontemporal_store(r1, (f32x4*)(po + 16));
        __builtin_nontemporal_store(r2, (f32x4*)(po + 32));
        __builtin_nontemporal_store(r3, (f32x4*)(po + 48));
    }
}

extern "C" void kernel_launch(void* const* d_in, const int* in_sizes, int n_in,
                              void* d_out, int out_size, void* d_ws, size_t ws_size,
                              hipStream_t stream) {
    const float* inputs = (const float*)d_in[0];
    const int*   t1i    = (const int*)d_in[1];
    const float* t1v    = (const float*)d_in[2];
    const int*   t2i    = (const int*)d_in[3];
    const float* t2v    = (const float*)d_in[4];
    const float* W      = (const float*)d_in[5];
    const float* bias   = (const float*)d_in[6];
    float* out = (float*)d_out;

    short* ws = (short*)d_ws;
    const size_t NF = (size_t)NN * FF;          // elements per slab
    short* x0  = ws;                 // m = 0
    short* xs1 = ws + 1 * NF;        // m = 1 (t1, x1)
    short* xs2 = ws + 2 * NF;        // m = 2 (t1, x2)
    short* xs3 = ws + 3 * NF;        // m = 3 (t2, x1)
    short* xs4 = ws + 4 * NF;        // m = 4 (t2, x2)
    short* wt  = ws + 5 * NF;        // [64][160] bf16
    int* cnt  = (int*)(wt + 64 * 160);              // 2*NN counters
    unsigned* ed1 = (unsigned*)(cnt + 2 * NN);      // NN*SLOTS packed 4B edges, graph 1
    unsigned* ed2 = ed1 + (size_t)NN * SLOTS;       // graph 2
    int* perm = (int*)(ed2 + (size_t)NN * SLOTS);   // 2*NN degree-sorted row ids (also prefetch slack)

    init_kernel<<<1280, 256, 0, stream>>>(ed1, cnt);
    pre_kernel<<<1 + 2500 + 625, 256, 0, stream>>>(inputs, x0, W, wt,
                                                   t1i, t1v, t2i, t2v, cnt, ed1, ed2);
    sort_kernel<<<2, 1024, 0, stream>>>(cnt, perm);

    const int spmm_grid = 2 * 625 * 8;   // 2 graphs x 625 row-blocks x 8 XCD chunks

    // step 1: x1 = A @ x0 (both transitions in one launch, XCD-affine chunks)
    spmm_kernel<<<spmm_grid, 256, 0, stream>>>(cnt, perm, ed1, ed2,
                                               x0, x0, xs1, xs3,
                                               nullptr, 1.0f);
    // step 2: x2 = 2 * (A @ x1) - x0 (fused Chebyshev epilogue)
    spmm_kernel<<<spmm_grid, 256, 0, stream>>>(cnt, perm, ed1, ed2,
                                               xs1, xs3, xs2, xs4,
                                               x0, 2.0f);

    gemm_mfma_kernel<<<1250, 256, 0, stream>>>(ws, wt, bias, out);
}